// Round 4
// baseline (51.564 us; speedup 1.0000x reference)
//
#include <hip/hip_runtime.h>

#define H_    1024
#define B_    512
#define OUT_  512
#define K_    1024

typedef _Float16 half8 __attribute__((ext_vector_type(8)));
typedef _Float16 half4 __attribute__((ext_vector_type(4)));
typedef float    f32x4 __attribute__((ext_vector_type(4)));

__device__ __forceinline__ void gl_lds16(const _Float16* g, _Float16* l) {
    __builtin_amdgcn_global_load_lds(
        (const __attribute__((address_space(1))) void*)g,
        (__attribute__((address_space(3))) void*)l, 16, 0, 0);
}

// ---------------------------------------------------------------------------
// f16 GEMM, C[bm..+128][bn..+64] = A @ Bt^T (+bias). BK=64, double-buffered
// LDS, global_load_lds width-16 staging. 4 waves (2x2), wave = 64x32 out.
// Swizzle (rule #21 compliant): LDS dest linear; SOURCE granule g = p^(row&7)
// pre-swizzled; reads use p = g^(row&7). Row&7 == lane>>3 on the write side.
// -> ds_read_b128 lands 2-way max per bank group (free, m136).
// ---------------------------------------------------------------------------
__device__ __forceinline__ void gemm_f16(const _Float16* __restrict__ A,
                                         const _Float16* __restrict__ Bt,
                                         const float* __restrict__ bias,
                                         float* __restrict__ C,
                                         int ldc, int bm, int bn)
{
    __shared__ __align__(16) _Float16 sA[2][128 * 64];
    __shared__ __align__(16) _Float16 sB[2][64 * 64];

    const int tid  = threadIdx.x;
    const int lane = tid & 63;
    const int w    = tid >> 6;
    const int wr   = w >> 1;              // 0..1 : 64-row half
    const int wc   = w & 1;               // 0..1 : 32-col half
    const int fr   = lane & 15;
    const int fg   = lane >> 4;           // k-granule within fragment

    // staging: source granule offset within a row (halves), same for all j
    const int sgo  = (((lane & 7) ^ (lane >> 3)) << 3);
    const int srA  = (lane >> 3) + (w << 5);   // base row this lane stages in A
    const int srB  = (lane >> 3) + (w << 4);   // and in B

    f32x4 acc[4][2] = {};

    auto stage = [&](int buf, int t) {
        const int k0 = t << 6;
#pragma unroll
        for (int j = 0; j < 4; ++j) {     // A: 128x64 halves, 4 instr/wave
            const _Float16* gp = A + (size_t)(bm + srA + j * 8) * K_ + k0 + sgo;
            gl_lds16(gp, &sA[buf][(w * 4 + j) * 512]);
        }
#pragma unroll
        for (int j = 0; j < 2; ++j) {     // B: 64x64 halves, 2 instr/wave
            const _Float16* gp = Bt + (size_t)(srB + j * 8) * K_ + k0 + sgo;
            gl_lds16(gp, &sB[buf][(w * 2 + j) * 512]);
        }
    };

    stage(0, 0);
    __syncthreads();

    int buf = 0;
    for (int t = 0; t < K_ / 64; ++t) {
        if (t + 1 < K_ / 64) stage(buf ^ 1, t + 1);

        const _Float16* a0 = &sA[buf][0];
        const _Float16* b0 = &sB[buf][0];
#pragma unroll
        for (int kh = 0; kh < 2; ++kh) {
            half8 af[4], bf[2];
#pragma unroll
            for (int mi = 0; mi < 4; ++mi) {
                int row = wr * 64 + mi * 16 + fr;
                int p   = ((kh * 4 + fg) ^ (fr & 7));
                af[mi] = *(const half8*)&a0[row * 64 + p * 8];
            }
#pragma unroll
            for (int ni = 0; ni < 2; ++ni) {
                int row = wc * 32 + ni * 16 + fr;
                int p   = ((kh * 4 + fg) ^ (fr & 7));
                bf[ni] = *(const half8*)&b0[row * 64 + p * 8];
            }
#pragma unroll
            for (int mi = 0; mi < 4; ++mi)
#pragma unroll
                for (int ni = 0; ni < 2; ++ni)
                    acc[mi][ni] = __builtin_amdgcn_mfma_f32_16x16x32_f16(
                                      af[mi], bf[ni], acc[mi][ni], 0, 0, 0);
        }
        __syncthreads();
        buf ^= 1;
    }

#pragma unroll
    for (int mi = 0; mi < 4; ++mi) {
        int row = bm + wr * 64 + mi * 16 + (lane >> 4) * 4;
#pragma unroll
        for (int ni = 0; ni < 2; ++ni) {
            int lcol = wc * 32 + ni * 16 + fr;
            float badd = bias ? bias[lcol] : 0.0f;
#pragma unroll
            for (int r = 0; r < 4; ++r)
                C[(size_t)(row + r) * ldc + bn + lcol] = acc[mi][ni][r] + badd;
        }
    }
}

// convert x, Wq|Wk|Wv, Wo to f16 (one BW-bound pass)
__global__ __launch_bounds__(256) void convert_kernel(const float* __restrict__ x,
                                                      const float* __restrict__ Wq,
                                                      const float* __restrict__ Wk,
                                                      const float* __restrict__ Wv,
                                                      const float* __restrict__ Wo,
                                                      _Float16* __restrict__ xh,
                                                      _Float16* __restrict__ Wh,
                                                      _Float16* __restrict__ Woh)
{
    const int g = blockIdx.x * 256 + threadIdx.x;      // one float4 per thread
    const float* src; _Float16* dst; int off;
    if (g < 262144)      { src = Wq; dst = Wh;           off = g; }
    else if (g < 524288) { src = Wk; dst = Wh + 1048576; off = g - 262144; }
    else if (g < 786432) { src = Wv; dst = Wh + 2097152; off = g - 524288; }
    else if (g < 917504) { src = x;  dst = xh;           off = g - 786432; }
    else                 { src = Wo; dst = Woh;          off = g - 917504; }
    float4 f = ((const float4*)src)[off];
    half4 h;
    h[0] = (_Float16)f.x; h[1] = (_Float16)f.y; h[2] = (_Float16)f.z; h[3] = (_Float16)f.w;
    ((half4*)dst)[off] = h;
}

__global__ __launch_bounds__(256) void qkv_kernel(const _Float16* __restrict__ xh,
                                                  const _Float16* __restrict__ Wh,
                                                  const float* __restrict__ bv,
                                                  float* __restrict__ qkv)
{
    const int bn = blockIdx.x * 64;
    const int bm = blockIdx.y * 128;
    const float* bias = (bn >= 2048) ? (bv + (bn - 2048)) : nullptr;
    gemm_f16(xh, Wh + (size_t)bn * K_, bias, qkv, 3072, bm, bn);
}

__global__ __launch_bounds__(256) void out_kernel(const _Float16* __restrict__ attnh,
                                                  const _Float16* __restrict__ Woh,
                                                  const float* __restrict__ bo,
                                                  float* __restrict__ C)
{
    const int bn = blockIdx.x * 64;
    const int bm = blockIdx.y * 128;
    gemm_f16(attnh, Woh + (size_t)bn * K_, bo + bn, C, OUT_, bm, bn);
}

// ---------------------------------------------------------------------------
// Fused rank-1 attention: per-batch Taylor moments (deg 7) + Horner eval.
// out[b,i] = N(c)/D(c), c = q[b,i]; N,D deg-7 polys from 16 per-batch moments
// of s_j = k[b,j]/32 (weights 1 and v_j).  |c*s| <= ~0.85, remainder < 2e-5.
// One block per batch; writes attn as f16 for the out GEMM.
// ---------------------------------------------------------------------------
__global__ __launch_bounds__(256) void attn_fused_kernel(const float* __restrict__ qkv,
                                                         _Float16* __restrict__ attnh)
{
    __shared__ float red[4][16];
    __shared__ float sm[16];
    const int b   = blockIdx.x;
    const int tid = threadIdx.x;

    float4 k4 = ((const float4*)(qkv + (size_t)b * 3072 + 1024))[tid];
    float4 v4 = ((const float4*)(qkv + (size_t)b * 3072 + 2048))[tid];

    float m[8] = {}, Mv[8] = {};
    const float ks[4] = {k4.x, k4.y, k4.z, k4.w};
    const float vs[4] = {v4.x, v4.y, v4.z, v4.w};
#pragma unroll
    for (int e = 0; e < 4; ++e) {
        float s = ks[e] * (1.0f / 32.0f);
        float v = vs[e];
        float p = 1.0f;
#pragma unroll
        for (int n = 0; n < 8; ++n) {
            m[n] += p;
            Mv[n] = fmaf(p, v, Mv[n]);
            p *= s;
        }
    }
#pragma unroll
    for (int off = 32; off; off >>= 1)
#pragma unroll
        for (int n = 0; n < 8; ++n) {
            m[n]  += __shfl_xor(m[n],  off, 64);
            Mv[n] += __shfl_xor(Mv[n], off, 64);
        }
    const int wave = tid >> 6;
    if ((tid & 63) == 0) {
#pragma unroll
        for (int n = 0; n < 8; ++n) {
            red[wave][n]     = m[n];
            red[wave][n + 8] = Mv[n];
        }
    }
    __syncthreads();
    if (tid < 16) {
        const float invfact[8] = {1.f, 1.f, 0.5f, 1.f/6.f, 1.f/24.f,
                                  1.f/120.f, 1.f/720.f, 1.f/5040.f};
        sm[tid] = (red[0][tid] + red[1][tid] + red[2][tid] + red[3][tid])
                  * invfact[tid & 7];
    }
    __syncthreads();

    float4 q4 = ((const float4*)(qkv + (size_t)b * 3072))[tid];
    const float cs[4] = {q4.x, q4.y, q4.z, q4.w};
    half4 o;
#pragma unroll
    for (int e = 0; e < 4; ++e) {
        float c = cs[e];
        float den = sm[7];
#pragma unroll
        for (int n = 6; n >= 0; --n) den = fmaf(den, c, sm[n]);
        float num = sm[15];
#pragma unroll
        for (int n = 14; n >= 8; --n) num = fmaf(num, c, sm[n]);
        o[e] = (_Float16)(num / den);
    }
    ((half4*)attnh)[b * 256 + tid] = o;
}

extern "C" void kernel_launch(void* const* d_in, const int* in_sizes, int n_in,
                              void* d_out, int out_size, void* d_ws, size_t ws_size,
                              hipStream_t stream)
{
    const float* x  = (const float*)d_in[0];
    const float* Wq = (const float*)d_in[1];
    const float* Wk = (const float*)d_in[2];
    const float* Wv = (const float*)d_in[3];
    const float* bv = (const float*)d_in[4];
    const float* Wo = (const float*)d_in[5];
    const float* bo = (const float*)d_in[6];
    float* out = (float*)d_out;

    // workspace layout (bytes): qkv f32 [512][3072] | attnh f16 | xh | Wh | Woh
    char* ws = (char*)d_ws;
    float*    qkv   = (float*)ws;                                   // 6 MB
    _Float16* attnh = (_Float16*)(ws + (6 << 20));                  // 1 MB
    _Float16* xh    = (_Float16*)(ws + (7 << 20));                  // 1 MB
    _Float16* Wh    = (_Float16*)(ws + (8 << 20));                  // 6 MB
    _Float16* Woh   = (_Float16*)(ws + (14 << 20));                 // 1 MB

    convert_kernel<<<dim3(4096), 256, 0, stream>>>(x, Wq, Wk, Wv, Wo, xh, Wh, Woh);
    qkv_kernel<<<dim3(48, 4), 256, 0, stream>>>(xh, Wh, bv, qkv);
    attn_fused_kernel<<<dim3(B_), 256, 0, stream>>>(qkv, attnh);
    out_kernel<<<dim3(8, 4), 256, 0, stream>>>(attnh, Woh, bo, out);
}

// Round 5
// 35.064 us; speedup vs baseline: 1.4705x; 1.4705x over previous
//
#include <hip/hip_runtime.h>

#define H_    1024
#define B_    512
#define OUT_  512

typedef _Float16 half8 __attribute__((ext_vector_type(8)));
typedef _Float16 half4 __attribute__((ext_vector_type(4)));
typedef float    f32x4 __attribute__((ext_vector_type(4)));

__device__ __forceinline__ half8 cvt8(float4 lo, float4 hi) {
    half8 h;
    h[0] = (_Float16)lo.x; h[1] = (_Float16)lo.y; h[2] = (_Float16)lo.z; h[3] = (_Float16)lo.w;
    h[4] = (_Float16)hi.x; h[5] = (_Float16)hi.y; h[6] = (_Float16)hi.z; h[7] = (_Float16)hi.w;
    return h;
}

// Workgroup barrier WITHOUT the vmcnt(0) drain __syncthreads() emits:
// waits only LDS ops; global prefetch loads stay in flight across it.
__device__ __forceinline__ void barrier_nodrain() {
    asm volatile("s_waitcnt lgkmcnt(0)" ::: "memory");
    __builtin_amdgcn_s_barrier();
}

// ---------------------------------------------------------------------------
// qkv with global K-split: qkvp[kz][B][3072] partial over K-half kz.
// 64x64 tiles, BK=64, 4 waves (2x2, each 32x32), grid (48, 8, 2) = 768 blocks.
// f32 global -> regs -> cvt f16 -> swizzled LDS (g' = g ^ (row&7): read side
// has row&7 == lane&7 -> 8 distinct granules per 8 lanes, 2-way max = free).
// Single barrier_nodrain per K-step; double-buffered LDS.
// No bias here (bv folded into attn_fused after partial sum).
// ---------------------------------------------------------------------------
__global__ __launch_bounds__(256) void qkv_kernel(const float* __restrict__ x,
                                                  const float* __restrict__ Wq,
                                                  const float* __restrict__ Wk,
                                                  const float* __restrict__ Wv,
                                                  float* __restrict__ qkvp)
{
    __shared__ __align__(16) _Float16 sA[2][64 * 64];
    __shared__ __align__(16) _Float16 sB[2][64 * 64];

    const int tid  = threadIdx.x;
    const int lane = tid & 63;
    const int w    = tid >> 6;
    const int wr   = w >> 1, wc = w & 1;
    const int fr   = lane & 15, fg = lane >> 4;

    const int bn = blockIdx.x * 64;      // 0..3071 (q|k|v concat)
    const int bm = blockIdx.y * 64;      // 0..511
    const int kz = blockIdx.z;           // K-half
    const int k0 = kz * 512;

    const int wsel = bn >> 10;
    const float* W = (wsel == 0) ? Wq : (wsel == 1) ? Wk : Wv;
    const int brow = bn & 1023;

    // staging: thread covers row=tid>>2, 16 cols at cq*16
    const int srow = tid >> 2;
    const int cq   = tid & 3;
    const float* Ap = x + (size_t)(bm + srow) * H_ + k0 + cq * 16;
    const float* Bp = W + (size_t)(brow + srow) * H_ + k0 + cq * 16;

    const int g0    = (((2 * cq)     ^ (srow & 7)) << 3);
    const int g1    = (((2 * cq + 1) ^ (srow & 7)) << 3);
    const int wbase = srow * 64;

    f32x4 acc[2][2] = {};

    float4 a0 = *(const float4*)(Ap + 0), a1 = *(const float4*)(Ap + 4);
    float4 a2 = *(const float4*)(Ap + 8), a3 = *(const float4*)(Ap + 12);
    float4 b0 = *(const float4*)(Bp + 0), b1 = *(const float4*)(Bp + 4);
    float4 b2 = *(const float4*)(Bp + 8), b3 = *(const float4*)(Bp + 12);

    for (int t = 0; t < 8; ++t) {
        const int buf = t & 1;
        // convert first (frees a0..b3 so prefetch can issue before ds_write)
        half8 hA0 = cvt8(a0, a1), hA1 = cvt8(a2, a3);
        half8 hB0 = cvt8(b0, b1), hB1 = cvt8(b2, b3);
        if (t < 7) {
            const float* An = Ap + (t + 1) * 64;
            const float* Bn = Bp + (t + 1) * 64;
            a0 = *(const float4*)(An + 0); a1 = *(const float4*)(An + 4);
            a2 = *(const float4*)(An + 8); a3 = *(const float4*)(An + 12);
            b0 = *(const float4*)(Bn + 0); b1 = *(const float4*)(Bn + 4);
            b2 = *(const float4*)(Bn + 8); b3 = *(const float4*)(Bn + 12);
        }
        *(half8*)&sA[buf][wbase + g0] = hA0;
        *(half8*)&sA[buf][wbase + g1] = hA1;
        *(half8*)&sB[buf][wbase + g0] = hB0;
        *(half8*)&sB[buf][wbase + g1] = hB1;
        barrier_nodrain();

#pragma unroll
        for (int kh = 0; kh < 2; ++kh) {
            const int p = (((kh * 4 + fg) ^ (fr & 7)) << 3);
            half8 af[2], bf[2];
#pragma unroll
            for (int mi = 0; mi < 2; ++mi)
                af[mi] = *(const half8*)&sA[buf][(wr * 32 + mi * 16 + fr) * 64 + p];
#pragma unroll
            for (int ni = 0; ni < 2; ++ni)
                bf[ni] = *(const half8*)&sB[buf][(wc * 32 + ni * 16 + fr) * 64 + p];
#pragma unroll
            for (int mi = 0; mi < 2; ++mi)
#pragma unroll
                for (int ni = 0; ni < 2; ++ni)
                    acc[mi][ni] = __builtin_amdgcn_mfma_f32_16x16x32_f16(
                                      af[mi], bf[ni], acc[mi][ni], 0, 0, 0);
        }
        // no trailing barrier: next iter writes the other buffer; same-buffer
        // reuse is 2 iters away, ordered by the next barrier.
    }

    float* Cb = qkvp + ((size_t)kz * B_ + bm) * 3072 + bn;
#pragma unroll
    for (int mi = 0; mi < 2; ++mi) {
        const int r0 = wr * 32 + mi * 16 + fg * 4;
#pragma unroll
        for (int ni = 0; ni < 2; ++ni) {
            const int col = wc * 32 + ni * 16 + fr;
#pragma unroll
            for (int r = 0; r < 4; ++r)
                Cb[(size_t)(r0 + r) * 3072 + col] = acc[mi][ni][r];
        }
    }
}

// ---------------------------------------------------------------------------
// Fused moments + eval, consuming the two K-partials (free reduction) and bv.
// s_j = k[b,j]/32, deg-7 Taylor: out[b,i] = N(c_i)/D(c_i), c = q[b,i].
// Writes attn as f16 for the out GEMM.
// ---------------------------------------------------------------------------
__global__ __launch_bounds__(256) void attn_fused_kernel(const float* __restrict__ qkvp,
                                                         const float* __restrict__ bv,
                                                         _Float16* __restrict__ attnh)
{
    __shared__ float red[4][16];
    __shared__ float sm[16];
    const int b   = blockIdx.x;
    const int tid = threadIdx.x;

    const float* p0 = qkvp + (size_t)b * 3072;
    const float* p1 = qkvp + (size_t)(B_ + b) * 3072;

    float4 ka = ((const float4*)(p0 + 1024))[tid];
    float4 kb = ((const float4*)(p1 + 1024))[tid];
    float4 va = ((const float4*)(p0 + 2048))[tid];
    float4 vb = ((const float4*)(p1 + 2048))[tid];
    float4 bv4 = ((const float4*)bv)[tid];

    const float ks[4] = {ka.x + kb.x, ka.y + kb.y, ka.z + kb.z, ka.w + kb.w};
    const float vs[4] = {va.x + vb.x + bv4.x, va.y + vb.y + bv4.y,
                         va.z + vb.z + bv4.z, va.w + vb.w + bv4.w};

    float m[8] = {}, Mv[8] = {};
#pragma unroll
    for (int e = 0; e < 4; ++e) {
        float s = ks[e] * (1.0f / 32.0f);
        float v = vs[e];
        float p = 1.0f;
#pragma unroll
        for (int n = 0; n < 8; ++n) {
            m[n] += p;
            Mv[n] = fmaf(p, v, Mv[n]);
            p *= s;
        }
    }
#pragma unroll
    for (int off = 32; off; off >>= 1)
#pragma unroll
        for (int n = 0; n < 8; ++n) {
            m[n]  += __shfl_xor(m[n],  off, 64);
            Mv[n] += __shfl_xor(Mv[n], off, 64);
        }
    const int wave = tid >> 6;
    if ((tid & 63) == 0) {
#pragma unroll
        for (int n = 0; n < 8; ++n) {
            red[wave][n]     = m[n];
            red[wave][n + 8] = Mv[n];
        }
    }
    __syncthreads();
    if (tid < 16) {
        const float invfact[8] = {1.f, 1.f, 0.5f, 1.f/6.f, 1.f/24.f,
                                  1.f/120.f, 1.f/720.f, 1.f/5040.f};
        sm[tid] = (red[0][tid] + red[1][tid] + red[2][tid] + red[3][tid])
                  * invfact[tid & 7];
    }
    __syncthreads();

    float4 qa = ((const float4*)p0)[tid];
    float4 qb = ((const float4*)p1)[tid];
    const float cs[4] = {qa.x + qb.x, qa.y + qb.y, qa.z + qb.z, qa.w + qb.w};
    half4 o;
#pragma unroll
    for (int e = 0; e < 4; ++e) {
        float c = cs[e];
        float den = sm[7];
#pragma unroll
        for (int n = 6; n >= 0; --n) den = fmaf(den, c, sm[n]);
        float num = sm[15];
#pragma unroll
        for (int n = 14; n >= 8; --n) num = fmaf(num, c, sm[n]);
        o[e] = (_Float16)(num / den);
    }
    ((half4*)attnh)[b * 256 + tid] = o;
}

// ---------------------------------------------------------------------------
// out = attn @ Wo^T + bo. 64x64 tiles, 8 waves with in-block K-split:
// waves 0-3 compute K[0:512), waves 4-7 K[512:1024), LDS reduce at the end.
// A = attnh (f16, direct), B = Wo (f32, reg-cvt). grid (8, 8) = 64 blocks.
// ---------------------------------------------------------------------------
__global__ __launch_bounds__(512) void out_kernel(const _Float16* __restrict__ attnh,
                                                  const float* __restrict__ Wo,
                                                  const float* __restrict__ bo,
                                                  float* __restrict__ outp)
{
    __shared__ __align__(16) _Float16 sA[2][2][64 * 64];   // [grp][buf]
    __shared__ __align__(16) _Float16 sB[2][2][64 * 64];

    const int tid  = threadIdx.x;
    const int lane = tid & 63;
    const int w    = tid >> 6;         // 0..7
    const int grp  = w >> 2;           // compute K-half
    const int wl   = w & 3;
    const int wr   = wl >> 1, wc = wl & 1;
    const int fr   = lane & 15, fg = lane >> 4;

    const int bn = blockIdx.x * 64;
    const int bm = blockIdx.y * 64;

    // staging: thread's staging group = tid>>8 (independent of compute grp)
    const int sgrp = tid >> 8;
    const int st   = tid & 255;
    const int srow = st >> 2;
    const int cq   = st & 3;
    const int k0   = sgrp * 512;

    const _Float16* Ap = attnh + (size_t)(bm + srow) * H_ + k0 + cq * 16;
    const float*    Bp = Wo    + (size_t)(bn + srow) * H_ + k0 + cq * 16;

    const int g0    = (((2 * cq)     ^ (srow & 7)) << 3);
    const int g1    = (((2 * cq + 1) ^ (srow & 7)) << 3);
    const int wbase = srow * 64;

    f32x4 acc[2][2] = {};

    half8  a0 = *(const half8*)(Ap + 0), a1 = *(const half8*)(Ap + 8);
    float4 b0 = *(const float4*)(Bp + 0), b1 = *(const float4*)(Bp + 4);
    float4 b2 = *(const float4*)(Bp + 8), b3 = *(const float4*)(Bp + 12);

    for (int t = 0; t < 8; ++t) {
        const int buf = t & 1;
        half8 hA0 = a0, hA1 = a1;
        half8 hB0 = cvt8(b0, b1), hB1 = cvt8(b2, b3);
        if (t < 7) {
            const _Float16* An = Ap + (t + 1) * 64;
            const float*    Bn = Bp + (t + 1) * 64;
            a0 = *(const half8*)(An + 0); a1 = *(const half8*)(An + 8);
            b0 = *(const float4*)(Bn + 0); b1 = *(const float4*)(Bn + 4);
            b2 = *(const float4*)(Bn + 8); b3 = *(const float4*)(Bn + 12);
        }
        *(half8*)&sA[sgrp][buf][wbase + g0] = hA0;
        *(half8*)&sA[sgrp][buf][wbase + g1] = hA1;
        *(half8*)&sB[sgrp][buf][wbase + g0] = hB0;
        *(half8*)&sB[sgrp][buf][wbase + g1] = hB1;
        barrier_nodrain();

#pragma unroll
        for (int kh = 0; kh < 2; ++kh) {
            const int p = (((kh * 4 + fg) ^ (fr & 7)) << 3);
            half8 af[2], bf[2];
#pragma unroll
            for (int mi = 0; mi < 2; ++mi)
                af[mi] = *(const half8*)&sA[grp][buf][(wr * 32 + mi * 16 + fr) * 64 + p];
#pragma unroll
            for (int ni = 0; ni < 2; ++ni)
                bf[ni] = *(const half8*)&sB[grp][buf][(wc * 32 + ni * 16 + fr) * 64 + p];
#pragma unroll
            for (int mi = 0; mi < 2; ++mi)
#pragma unroll
                for (int ni = 0; ni < 2; ++ni)
                    acc[mi][ni] = __builtin_amdgcn_mfma_f32_16x16x32_f16(
                                      af[mi], bf[ni], acc[mi][ni], 0, 0, 0);
        }
    }

    // cross-group reduction through LDS (reuse sA area: 64x64 f32 = 16 KB)
    __syncthreads();
    float* red = (float*)&sA[0][0][0];
    if (grp == 1) {
#pragma unroll
        for (int mi = 0; mi < 2; ++mi)
#pragma unroll
            for (int ni = 0; ni < 2; ++ni)
#pragma unroll
                for (int r = 0; r < 4; ++r)
                    red[(wr * 32 + mi * 16 + fg * 4 + r) * 64 +
                        (wc * 32 + ni * 16 + fr)] = acc[mi][ni][r];
    }
    __syncthreads();
    if (grp == 0) {
#pragma unroll
        for (int mi = 0; mi < 2; ++mi) {
            const int r0 = wr * 32 + mi * 16 + fg * 4;
#pragma unroll
            for (int ni = 0; ni < 2; ++ni) {
                const int col = wc * 32 + ni * 16 + fr;
                const float badd = bo[bn + col];
#pragma unroll
                for (int r = 0; r < 4; ++r) {
                    float v = acc[mi][ni][r] +
                              red[(r0 + r) * 64 + col] + badd;
                    outp[(size_t)(bm + r0 + r) * OUT_ + bn + col] = v;
                }
            }
        }
    }
}

extern "C" void kernel_launch(void* const* d_in, const int* in_sizes, int n_in,
                              void* d_out, int out_size, void* d_ws, size_t ws_size,
                              hipStream_t stream)
{
    const float* x  = (const float*)d_in[0];
    const float* Wq = (const float*)d_in[1];
    const float* Wk = (const float*)d_in[2];
    const float* Wv = (const float*)d_in[3];
    const float* bv = (const float*)d_in[4];
    const float* Wo = (const float*)d_in[5];
    const float* bo = (const float*)d_in[6];
    float* out = (float*)d_out;

    char* ws = (char*)d_ws;
    float*    qkvp  = (float*)ws;                       // [2][512][3072] f32 = 12 MB
    _Float16* attnh = (_Float16*)(ws + (12 << 20));     // [512][1024] f16 = 1 MB

    qkv_kernel<<<dim3(48, 8, 2), 256, 0, stream>>>(x, Wq, Wk, Wv, qkvp);
    attn_fused_kernel<<<dim3(B_), 256, 0, stream>>>(qkvp, bv, attnh);
    out_kernel<<<dim3(8, 8), 512, 0, stream>>>(attnh, Wo, bo, out);
}

// Round 6
// 32.275 us; speedup vs baseline: 1.5976x; 1.0864x over previous
//
#include <hip/hip_runtime.h>

#define H_    1024
#define B_    512
#define OUT_  512

typedef _Float16 half8 __attribute__((ext_vector_type(8)));
typedef _Float16 half4 __attribute__((ext_vector_type(4)));
typedef float    f32x4 __attribute__((ext_vector_type(4)));

__device__ __forceinline__ half8 cvt8(float4 lo, float4 hi) {
    half8 h;
    h[0] = (_Float16)lo.x; h[1] = (_Float16)lo.y; h[2] = (_Float16)lo.z; h[3] = (_Float16)lo.w;
    h[4] = (_Float16)hi.x; h[5] = (_Float16)hi.y; h[6] = (_Float16)hi.z; h[7] = (_Float16)hi.w;
    return h;
}

// Workgroup barrier WITHOUT the vmcnt(0) drain __syncthreads() emits:
// waits only LDS ops; global prefetch loads stay in flight across it.
__device__ __forceinline__ void barrier_nodrain() {
    asm volatile("s_waitcnt lgkmcnt(0)" ::: "memory");
    __builtin_amdgcn_s_barrier();
}

// ---------------------------------------------------------------------------
// qkv with global K-split: qkvp[kz][B][3072] partial over K-half kz.
// 64x64 tiles, BK=64, 4 waves (2x2, each 32x32), 768 jobs.
// Job decode is bm-FASTEST + XCD-chunked swizzle: XCD c owns jobs
// [c*96, c*96+96) = {all 8 bm} x {12 bn} x {1 kz} -> per-XCD L2 working set
// = 1 MB x-half + 12 x 128 KB W-col-halves = 2.5 MB < 4 MB L2.
// ---------------------------------------------------------------------------
__global__ __launch_bounds__(256) void qkv_kernel(const float* __restrict__ x,
                                                  const float* __restrict__ Wq,
                                                  const float* __restrict__ Wk,
                                                  const float* __restrict__ Wv,
                                                  float* __restrict__ qkvp)
{
    __shared__ __align__(16) _Float16 sA[2][64 * 64];
    __shared__ __align__(16) _Float16 sB[2][64 * 64];

    const int tid  = threadIdx.x;
    const int lane = tid & 63;
    const int w    = tid >> 6;
    const int wr   = w >> 1, wc = w & 1;
    const int fr   = lane & 15, fg = lane >> 4;

    // XCD-chunked job swizzle (768 = 8 * 96, bijective)
    const int d    = blockIdx.x;
    const int job  = (d & 7) * 96 + (d >> 3);
    const int bm   = (job & 7) * 64;          // bm fastest
    const int rest = job >> 3;                // 0..95
    const int kz   = (rest >= 48) ? 1 : 0;
    const int bn   = (rest - kz * 48) * 64;   // 0..3071
    const int k0   = kz * 512;

    const int wsel = bn >> 10;
    const float* W = (wsel == 0) ? Wq : (wsel == 1) ? Wk : Wv;
    const int brow = bn & 1023;

    const int srow = tid >> 2;
    const int cq   = tid & 3;
    const float* Ap = x + (size_t)(bm + srow) * H_ + k0 + cq * 16;
    const float* Bp = W + (size_t)(brow + srow) * H_ + k0 + cq * 16;

    const int g0    = (((2 * cq)     ^ (srow & 7)) << 3);
    const int g1    = (((2 * cq + 1) ^ (srow & 7)) << 3);
    const int wbase = srow * 64;

    f32x4 acc[2][2] = {};

    float4 a0 = *(const float4*)(Ap + 0), a1 = *(const float4*)(Ap + 4);
    float4 a2 = *(const float4*)(Ap + 8), a3 = *(const float4*)(Ap + 12);
    float4 b0 = *(const float4*)(Bp + 0), b1 = *(const float4*)(Bp + 4);
    float4 b2 = *(const float4*)(Bp + 8), b3 = *(const float4*)(Bp + 12);

    for (int t = 0; t < 8; ++t) {
        const int buf = t & 1;
        half8 hA0 = cvt8(a0, a1), hA1 = cvt8(a2, a3);
        half8 hB0 = cvt8(b0, b1), hB1 = cvt8(b2, b3);
        if (t < 7) {
            const float* An = Ap + (t + 1) * 64;
            const float* Bn = Bp + (t + 1) * 64;
            a0 = *(const float4*)(An + 0); a1 = *(const float4*)(An + 4);
            a2 = *(const float4*)(An + 8); a3 = *(const float4*)(An + 12);
            b0 = *(const float4*)(Bn + 0); b1 = *(const float4*)(Bn + 4);
            b2 = *(const float4*)(Bn + 8); b3 = *(const float4*)(Bn + 12);
        }
        *(half8*)&sA[buf][wbase + g0] = hA0;
        *(half8*)&sA[buf][wbase + g1] = hA1;
        *(half8*)&sB[buf][wbase + g0] = hB0;
        *(half8*)&sB[buf][wbase + g1] = hB1;
        barrier_nodrain();

#pragma unroll
        for (int kh = 0; kh < 2; ++kh) {
            const int p = (((kh * 4 + fg) ^ (fr & 7)) << 3);
            half8 af[2], bf[2];
#pragma unroll
            for (int mi = 0; mi < 2; ++mi)
                af[mi] = *(const half8*)&sA[buf][(wr * 32 + mi * 16 + fr) * 64 + p];
#pragma unroll
            for (int ni = 0; ni < 2; ++ni)
                bf[ni] = *(const half8*)&sB[buf][(wc * 32 + ni * 16 + fr) * 64 + p];
#pragma unroll
            for (int mi = 0; mi < 2; ++mi)
#pragma unroll
                for (int ni = 0; ni < 2; ++ni)
                    acc[mi][ni] = __builtin_amdgcn_mfma_f32_16x16x32_f16(
                                      af[mi], bf[ni], acc[mi][ni], 0, 0, 0);
        }
    }

    float* Cb = qkvp + ((size_t)kz * B_ + bm) * 3072 + bn;
#pragma unroll
    for (int mi = 0; mi < 2; ++mi) {
        const int r0 = wr * 32 + mi * 16 + fg * 4;
#pragma unroll
        for (int ni = 0; ni < 2; ++ni) {
            const int col = wc * 32 + ni * 16 + fr;
#pragma unroll
            for (int r = 0; r < 4; ++r)
                Cb[(size_t)(r0 + r) * 3072 + col] = acc[mi][ni][r];
        }
    }
}

// ---------------------------------------------------------------------------
// Fused moments + eval, consuming the two K-partials (free reduction) and bv.
// s_j = k[b,j]/32, deg-7 Taylor: out[b,i] = N(c_i)/D(c_i), c = q[b,i].
// Writes attn as f16 for the out GEMM.
// ---------------------------------------------------------------------------
__global__ __launch_bounds__(256) void attn_fused_kernel(const float* __restrict__ qkvp,
                                                         const float* __restrict__ bv,
                                                         _Float16* __restrict__ attnh)
{
    __shared__ float red[4][16];
    __shared__ float sm[16];
    const int b   = blockIdx.x;
    const int tid = threadIdx.x;

    const float* p0 = qkvp + (size_t)b * 3072;
    const float* p1 = qkvp + (size_t)(B_ + b) * 3072;

    float4 ka = ((const float4*)(p0 + 1024))[tid];
    float4 kb = ((const float4*)(p1 + 1024))[tid];
    float4 va = ((const float4*)(p0 + 2048))[tid];
    float4 vb = ((const float4*)(p1 + 2048))[tid];
    float4 bv4 = ((const float4*)bv)[tid];

    const float ks[4] = {ka.x + kb.x, ka.y + kb.y, ka.z + kb.z, ka.w + kb.w};
    const float vs[4] = {va.x + vb.x + bv4.x, va.y + vb.y + bv4.y,
                         va.z + vb.z + bv4.z, va.w + vb.w + bv4.w};

    float m[8] = {}, Mv[8] = {};
#pragma unroll
    for (int e = 0; e < 4; ++e) {
        float s = ks[e] * (1.0f / 32.0f);
        float v = vs[e];
        float p = 1.0f;
#pragma unroll
        for (int n = 0; n < 8; ++n) {
            m[n] += p;
            Mv[n] = fmaf(p, v, Mv[n]);
            p *= s;
        }
    }
#pragma unroll
    for (int off = 32; off; off >>= 1)
#pragma unroll
        for (int n = 0; n < 8; ++n) {
            m[n]  += __shfl_xor(m[n],  off, 64);
            Mv[n] += __shfl_xor(Mv[n], off, 64);
        }
    const int wave = tid >> 6;
    if ((tid & 63) == 0) {
#pragma unroll
        for (int n = 0; n < 8; ++n) {
            red[wave][n]     = m[n];
            red[wave][n + 8] = Mv[n];
        }
    }
    __syncthreads();
    if (tid < 16) {
        const float invfact[8] = {1.f, 1.f, 0.5f, 1.f/6.f, 1.f/24.f,
                                  1.f/120.f, 1.f/720.f, 1.f/5040.f};
        sm[tid] = (red[0][tid] + red[1][tid] + red[2][tid] + red[3][tid])
                  * invfact[tid & 7];
    }
    __syncthreads();

    float4 qa = ((const float4*)p0)[tid];
    float4 qb = ((const float4*)p1)[tid];
    const float cs[4] = {qa.x + qb.x, qa.y + qb.y, qa.z + qb.z, qa.w + qb.w};
    half4 o;
#pragma unroll
    for (int e = 0; e < 4; ++e) {
        float c = cs[e];
        float den = sm[7];
#pragma unroll
        for (int n = 6; n >= 0; --n) den = fmaf(den, c, sm[n]);
        float num = sm[15];
#pragma unroll
        for (int n = 14; n >= 8; --n) num = fmaf(num, c, sm[n]);
        o[e] = (_Float16)(num / den);
    }
    ((half4*)attnh)[b * 256 + tid] = o;
}

// ---------------------------------------------------------------------------
// out = attn @ Wo^T + bo. BM=BN=32, 256 blocks (1/CU), chain 16 (BK=64).
// A staged as pure f16 copy from attnh; B = Wo f32 reg-cvt. Direct write.
// XCD-chunked: XCD c owns {all 16 bm} x {2 bn} -> attnh 1 MB + 2 Wo-col
// tiles in L2. 4 waves, each one 16x16 fragment.
// ---------------------------------------------------------------------------
__global__ __launch_bounds__(256) void out_kernel(const _Float16* __restrict__ attnh,
                                                  const float* __restrict__ Wo,
                                                  const float* __restrict__ bo,
                                                  float* __restrict__ outp)
{
    __shared__ __align__(16) _Float16 sA[2][32 * 64];
    __shared__ __align__(16) _Float16 sB[2][32 * 64];

    const int tid  = threadIdx.x;
    const int lane = tid & 63;
    const int w    = tid >> 6;
    const int wr   = w >> 1, wc = w & 1;
    const int fr   = lane & 15, fg = lane >> 4;

    const int d   = blockIdx.x;
    const int job = (d & 7) * 32 + (d >> 3);   // 256 = 8 * 32, bijective
    const int bm  = (job & 15) * 32;           // bm fastest
    const int bn  = (job >> 4) * 32;

    const int srow = tid >> 3;                 // 0..31
    const int cg   = tid & 7;                  // granule 0..7
    const _Float16* Ap = attnh + (size_t)(bm + srow) * H_ + cg * 8;
    const float*    Bp = Wo    + (size_t)(bn + srow) * H_ + cg * 8;

    const int sw    = (cg ^ (srow & 7)) << 3;
    const int wbase = srow * 64;

    f32x4 acc = {};

    half8  a0 = *(const half8*)Ap;
    float4 b0 = *(const float4*)(Bp + 0), b1 = *(const float4*)(Bp + 4);

    for (int t = 0; t < 16; ++t) {
        const int buf = t & 1;
        half8 hA = a0;
        half8 hB = cvt8(b0, b1);
        if (t < 15) {
            a0 = *(const half8*)(Ap + (t + 1) * 64);
            b0 = *(const float4*)(Bp + (t + 1) * 64);
            b1 = *(const float4*)(Bp + (t + 1) * 64 + 4);
        }
        *(half8*)&sA[buf][wbase + sw] = hA;
        *(half8*)&sB[buf][wbase + sw] = hB;
        barrier_nodrain();

#pragma unroll
        for (int kh = 0; kh < 2; ++kh) {
            const int p = (((kh * 4 + fg) ^ (fr & 7)) << 3);
            half8 af = *(const half8*)&sA[buf][(wr * 16 + fr) * 64 + p];
            half8 bf = *(const half8*)&sB[buf][(wc * 16 + fr) * 64 + p];
            acc = __builtin_amdgcn_mfma_f32_16x16x32_f16(af, bf, acc, 0, 0, 0);
        }
    }

    const int row0 = bm + wr * 16 + fg * 4;
    const int col  = bn + wc * 16 + fr;
    const float badd = bo[col];
#pragma unroll
    for (int r = 0; r < 4; ++r)
        outp[(size_t)(row0 + r) * OUT_ + col] = acc[r] + badd;
}

extern "C" void kernel_launch(void* const* d_in, const int* in_sizes, int n_in,
                              void* d_out, int out_size, void* d_ws, size_t ws_size,
                              hipStream_t stream)
{
    const float* x  = (const float*)d_in[0];
    const float* Wq = (const float*)d_in[1];
    const float* Wk = (const float*)d_in[2];
    const float* Wv = (const float*)d_in[3];
    const float* bv = (const float*)d_in[4];
    const float* Wo = (const float*)d_in[5];
    const float* bo = (const float*)d_in[6];
    float* out = (float*)d_out;

    char* ws = (char*)d_ws;
    float*    qkvp  = (float*)ws;                       // [2][512][3072] f32 = 12 MB
    _Float16* attnh = (_Float16*)(ws + (12 << 20));     // [512][1024] f16 = 1 MB

    qkv_kernel<<<dim3(768), 256, 0, stream>>>(x, Wq, Wk, Wv, qkvp);
    attn_fused_kernel<<<dim3(B_), 256, 0, stream>>>(qkvp, bv, attnh);
    out_kernel<<<dim3(256), 256, 0, stream>>>(attnh, Wo, bo, out);
}